// Round 7
// baseline (175.132 us; speedup 1.0000x reference)
//
#include <hip/hip_runtime.h>
#include <cstdint>
#include <cstddef>

#define WD  50
#define MT  256
#define BSZ 4096
#define NCH 8                  // batch chunks per (m,branch)
#define BCH (BSZ / NCH)        // 512 rows per block
#define ITERS (BCH / 4 / 16)   // 8 iters: per wave 128 rows, 16/iter

typedef __bf16 bf16x8 __attribute__((ext_vector_type(8)));
typedef float  f32x4  __attribute__((ext_vector_type(4)));

__device__ __forceinline__ float swishf(float x) {
    // x * sigmoid(x) via v_rcp_f32 (rel err ~1e-5, noise vs bf16 rounding)
    return x * __builtin_amdgcn_rcpf(1.0f + __expf(-x));
}

// Fused 1->50->50->1 MLP, layer-2 on bf16 MFMA (16x16x32), one branch.
// Block = (m, batch-chunk). 4 waves; each wave: 16 batch rows per iter.
// A (h1):  lane l -> row b=l&15,  k=(l>>4)*8+e  (computed in-register)
// B (W2^T):lane l -> col v=l&15,  k=(l>>4)*8+e  (static, 8 frags; k-perm
//          cancels between A and B since both use the same k map)
// D:       col v=l&15, row=(l>>4)*4+g           [m89-verified]
// MODE 0: out[m*BSZ + b]            (ws plane, caller pre-offsets by branch)
// MODE 1: out[(b*MT + m)*2 + br]    (direct interleaved pairs)
// MODE 2: out[b*MT + m]             (direct single-float)
template<int MODE>
__global__ __launch_bounds__(256, 8) void rmat_mlp_mfma(
    const float* __restrict__ U,
    const float* __restrict__ W1, const float* __restrict__ B1,
    const float* __restrict__ W2, const float* __restrict__ B2,
    const float* __restrict__ W3, const float* __restrict__ B3,
    float* __restrict__ out, int br)
{
    const int m  = blockIdx.x >> 3;        // 0..255
    const int ch = blockIdx.x & 7;         // 0..7

    const float* __restrict__ w1 = W1 + m * WD;
    const float* __restrict__ b1 = B1 + m * WD;
    const float* __restrict__ w2 = W2 + (size_t)m * WD * WD;
    const float* __restrict__ b2 = B2 + m * WD;
    const float* __restrict__ w3 = W3 + m * WD;
    const float  b3v = B3[m];

    const int lane = threadIdx.x & 63;
    const int wid  = threadIdx.x >> 6;
    const int lr   = lane & 15;            // A-row / D-col(v)
    const int lg   = lane >> 4;            // k-group / D-row-group

    // ---- static per-lane state (one-time prologue) ----
    bf16x8 wfrag[4][2];                    // W2^T: 4 v-tiles x 2 k-tiles
#pragma unroll
    for (int vt = 0; vt < 4; ++vt) {
        const int v = vt * 16 + lr;
#pragma unroll
        for (int kt = 0; kt < 2; ++kt)
#pragma unroll
            for (int e = 0; e < 8; ++e) {
                const int k = kt * 32 + lg * 8 + e;
                const float w = (v < WD && k < WD) ? w2[v * WD + k] : 0.0f;
                wfrag[vt][kt][e] = (__bf16)w;
            }
    }
    float w1v[16], b1v[16];                // this lane's 16 k slots
#pragma unroll
    for (int kt = 0; kt < 2; ++kt)
#pragma unroll
        for (int e = 0; e < 8; ++e) {
            const int k = kt * 32 + lg * 8 + e;
            w1v[kt * 8 + e] = (k < WD) ? w1[k] : 0.0f;
            b1v[kt * 8 + e] = (k < WD) ? b1[k] : 0.0f;
        }
    float b2v[4], w3v[4];                  // this lane's v per v-tile
#pragma unroll
    for (int vt = 0; vt < 4; ++vt) {
        const int v = vt * 16 + lr;
        b2v[vt] = (v < WD) ? b2[v] : 0.0f;
        w3v[vt] = (v < WD) ? w3[v] : 0.0f;
    }

    float* __restrict__ dst = out + (size_t)m * BSZ;   // MODE 0 base
    const int b0 = ch * BCH + wid * (BCH / 4);         // wave's 128-row slice

#pragma unroll 1
    for (int it = 0; it < ITERS; ++it) {
        const int bb = b0 + it * 16;
        const float u = U[bb + lr];

        // layer 1 -> A fragments; scalar (__bf16) casts pair into cvt_pk
        bf16x8 a0, a1;
#pragma unroll
        for (int e = 0; e < 8; ++e)
            a0[e] = (__bf16)swishf(fmaf(u, w1v[e], b1v[e]));
#pragma unroll
        for (int e = 0; e < 8; ++e)
            a1[e] = (__bf16)swishf(fmaf(u, w1v[8 + e], b1v[8 + e]));

        // layer 2 on the matrix pipe: 4 v-tiles x K=64
        f32x4 acc[4];
#pragma unroll
        for (int vt = 0; vt < 4; ++vt) {
            acc[vt] = (f32x4){0.f, 0.f, 0.f, 0.f};
            acc[vt] = __builtin_amdgcn_mfma_f32_16x16x32_bf16(a0, wfrag[vt][0], acc[vt], 0, 0, 0);
            acc[vt] = __builtin_amdgcn_mfma_f32_16x16x32_bf16(a1, wfrag[vt][1], acc[vt], 0, 0, 0);
        }

        // layer 3: swish + w3 dot, reduce across the 16 v-lanes
        float part[4];
#pragma unroll
        for (int g = 0; g < 4; ++g) {
            float p = 0.0f;
#pragma unroll
            for (int vt = 0; vt < 4; ++vt)
                p = fmaf(swishf(acc[vt][g] + b2v[vt]), w3v[vt], p);
            part[g] = p;
        }
#pragma unroll
        for (int g = 0; g < 4; ++g) {
            part[g] += __shfl_xor(part[g], 1);
            part[g] += __shfl_xor(part[g], 2);
            part[g] += __shfl_xor(part[g], 4);
            part[g] += __shfl_xor(part[g], 8);
        }

        if (lr == 0) {
            const int row = bb + lg * 4;
            if (MODE == 0) {
                *reinterpret_cast<float4*>(dst + row) =
                    make_float4(part[0] + b3v, part[1] + b3v,
                                part[2] + b3v, part[3] + b3v);
            } else if (MODE == 1) {
#pragma unroll
                for (int g = 0; g < 4; ++g)
                    out[((size_t)(row + g) * MT + m) * 2 + br] = part[g] + b3v;
            } else {
#pragma unroll
                for (int g = 0; g < 4; ++g)
                    out[(size_t)(row + g) * MT + m] = part[g] + b3v;
            }
        }
    }
}

// ws[NBR][256][4096] -> out. NBR=2: [b][m][re,im]; NBR=1: transpose to [b][m].
// (Verbatim from the round-2/5/6 PASS.)
template<int NBR>
__global__ __launch_bounds__(256) void rmat_interleave(
    const float* __restrict__ ws, float* __restrict__ out)
{
    __shared__ float tile[NBR][32][64 + 1];
    const int bt = blockIdx.x & 63;
    const int mt = blockIdx.x >> 6;
    const int b0 = bt * 64, m0 = mt * 32;

    for (int i = threadIdx.x; i < NBR * 32 * 64; i += 256) {
        const int brx = i >> 11;           // 0 when NBR==1
        const int r   = (i >> 6) & 31;
        const int c   = i & 63;
        tile[brx][r][c] = ws[(size_t)(brx * MT + m0 + r) * BSZ + b0 + c];
    }
    __syncthreads();

    const int tb   = threadIdx.x >> 2;
    const int part = threadIdx.x & 3;
    const int b = b0 + tb;
    if (NBR == 2) {
        float2* __restrict__ dstp =
            reinterpret_cast<float2*>(out) + (size_t)b * MT + m0 + part * 8;
#pragma unroll
        for (int k = 0; k < 8; ++k) {
            const int mm = part * 8 + k;
            dstp[k] = make_float2(tile[0][mm][tb], tile[1][mm][tb]);
        }
    } else {
        float* __restrict__ dstp = out + (size_t)b * MT + m0 + part * 8;
#pragma unroll
        for (int k = 0; k < 8; ++k)
            dstp[k] = tile[0][part * 8 + k][tb];
    }
}

extern "C" void kernel_launch(void* const* d_in, const int* in_sizes, int n_in,
                              void* d_out, int out_size, void* d_ws, size_t ws_size,
                              hipStream_t stream) {
    const float* U   = (const float*)d_in[0];
    const float* W1r = (const float*)d_in[1];
    const float* b1r = (const float*)d_in[2];
    const float* W2r = (const float*)d_in[3];
    const float* b2r = (const float*)d_in[4];
    const float* W3r = (const float*)d_in[5];
    const float* b3r = (const float*)d_in[6];
    const float* W1i = (const float*)d_in[7];
    const float* b1i = (const float*)d_in[8];
    const float* W2i = (const float*)d_in[9];
    const float* b2i = (const float*)d_in[10];
    const float* W3i = (const float*)d_in[11];
    const float* b3i = (const float*)d_in[12];
    float* out = (float*)d_out;
    float* ws  = (float*)d_ws;

    const dim3 grid(MT * NCH), block(256);
    const size_t plane = (size_t)MT * BSZ;   // floats per branch

    if (out_size >= (int)(2 * plane)) {
        // d_out = [B][M] of (re,im) float pairs
        if (ws_size >= 2 * plane * sizeof(float)) {
            rmat_mlp_mfma<0><<<grid, block, 0, stream>>>(U, W1r, b1r, W2r, b2r, W3r, b3r, ws, 0);
            rmat_mlp_mfma<0><<<grid, block, 0, stream>>>(U, W1i, b1i, W2i, b2i, W3i, b3i, ws + plane, 1);
            rmat_interleave<2><<<dim3(512), block, 0, stream>>>(ws, out);
        } else {
            rmat_mlp_mfma<1><<<grid, block, 0, stream>>>(U, W1r, b1r, W2r, b2r, W3r, b3r, out, 0);
            rmat_mlp_mfma<1><<<grid, block, 0, stream>>>(U, W1i, b1i, W2i, b2i, W3i, b3i, out, 1);
        }
    } else {
        // d_out holds B*M float32 -> real branch only (harness drops imag)
        if (ws_size >= plane * sizeof(float)) {
            rmat_mlp_mfma<0><<<grid, block, 0, stream>>>(U, W1r, b1r, W2r, b2r, W3r, b3r, ws, 0);
            rmat_interleave<1><<<dim3(512), block, 0, stream>>>(ws, out);
        } else {
            rmat_mlp_mfma<2><<<grid, block, 0, stream>>>(U, W1r, b1r, W2r, b2r, W3r, b3r, out, 0);
        }
    }
}

// Round 8
// 54.558 us; speedup vs baseline: 3.2100x; 3.2100x over previous
//
#include <hip/hip_runtime.h>
#include <cstdint>
#include <cstddef>

#define WD  50
#define MT  256
#define BSZ 4096
#define NCH 8                  // batch chunks per (m,branch): 2048 blocks
#define BCH (BSZ / NCH)        // 512 rows per block
#define ITERS (BCH / 4 / 16)   // 8 iters: per wave 128 rows, 16/iter

typedef __bf16 bf16x8 __attribute__((ext_vector_type(8)));
typedef float  f32x4  __attribute__((ext_vector_type(4)));

__device__ __forceinline__ float swishf(float x) {
    // x * sigmoid(x) via v_rcp_f32 (rel err ~1e-5, noise vs bf16 rounding)
    return x * __builtin_amdgcn_rcpf(1.0f + __expf(-x));
}

// Fused 1->50->50->1 MLP, layer-2 on bf16 MFMA (16x16x32), one branch.
// Block = (m, batch-chunk). 4 waves; each wave: 16 batch rows per iter.
// A (h1):  lane l -> row b=l&15,  k=(l>>4)*8+e  (computed in-register)
// B (W2^T):lane l -> col v=l&15,  k=(l>>4)*8+e  (static, 8 frags; k-perm
//          cancels between A and B since both use the same k map)
// D:       col v=l&15, row=(l>>4)*4+g           [m89-verified]
// NOTE round-7 lesson: __launch_bounds__ stays at 4 waves/EU — the (256,8)
// cap forced VGPR 60->32 and spilled wfrag to scratch (FETCH 5.8->432 MB).
// Occupancy comes from the grid instead: 2048 blocks = 8 blocks/CU, and
// VGPR=60 <= 64 lets HW co-schedule 8 waves/SIMD anyway.
// MODE 0: out[m*BSZ + b]            (ws plane, caller pre-offsets by branch)
// MODE 1: out[(b*MT + m)*2 + br]    (direct interleaved pairs)
// MODE 2: out[b*MT + m]             (direct single-float)
template<int MODE>
__global__ __launch_bounds__(256, 4) void rmat_mlp_mfma(
    const float* __restrict__ U,
    const float* __restrict__ W1, const float* __restrict__ B1,
    const float* __restrict__ W2, const float* __restrict__ B2,
    const float* __restrict__ W3, const float* __restrict__ B3,
    float* __restrict__ out, int br)
{
    const int m  = blockIdx.x >> 3;        // 0..255
    const int ch = blockIdx.x & 7;         // 0..7

    const float* __restrict__ w1 = W1 + m * WD;
    const float* __restrict__ b1 = B1 + m * WD;
    const float* __restrict__ w2 = W2 + (size_t)m * WD * WD;
    const float* __restrict__ b2 = B2 + m * WD;
    const float* __restrict__ w3 = W3 + m * WD;
    const float  b3v = B3[m];

    const int lane = threadIdx.x & 63;
    const int wid  = threadIdx.x >> 6;
    const int lr   = lane & 15;            // A-row / D-col(v)
    const int lg   = lane >> 4;            // k-group / D-row-group

    // ---- static per-lane state (one-time prologue) ----
    bf16x8 wfrag[4][2];                    // W2^T: 4 v-tiles x 2 k-tiles
#pragma unroll
    for (int vt = 0; vt < 4; ++vt) {
        const int v = vt * 16 + lr;
#pragma unroll
        for (int kt = 0; kt < 2; ++kt)
#pragma unroll
            for (int e = 0; e < 8; ++e) {
                const int k = kt * 32 + lg * 8 + e;
                const float w = (v < WD && k < WD) ? w2[v * WD + k] : 0.0f;
                wfrag[vt][kt][e] = (__bf16)w;
            }
    }
    float w1v[16], b1v[16];                // this lane's 16 k slots
#pragma unroll
    for (int kt = 0; kt < 2; ++kt)
#pragma unroll
        for (int e = 0; e < 8; ++e) {
            const int k = kt * 32 + lg * 8 + e;
            w1v[kt * 8 + e] = (k < WD) ? w1[k] : 0.0f;
            b1v[kt * 8 + e] = (k < WD) ? b1[k] : 0.0f;
        }
    float b2v[4], w3v[4];                  // this lane's v per v-tile
#pragma unroll
    for (int vt = 0; vt < 4; ++vt) {
        const int v = vt * 16 + lr;
        b2v[vt] = (v < WD) ? b2[v] : 0.0f;
        w3v[vt] = (v < WD) ? w3[v] : 0.0f;
    }

    float* __restrict__ dst = out + (size_t)m * BSZ;   // MODE 0 base
    const int b0 = ch * BCH + wid * (BCH / 4);         // wave's 128-row slice

#pragma unroll 1
    for (int it = 0; it < ITERS; ++it) {
        const int bb = b0 + it * 16;
        const float u = U[bb + lr];

        // layer 1 -> A fragments; scalar (__bf16) casts pair into cvt_pk
        bf16x8 a0, a1;
#pragma unroll
        for (int e = 0; e < 8; ++e)
            a0[e] = (__bf16)swishf(fmaf(u, w1v[e], b1v[e]));
#pragma unroll
        for (int e = 0; e < 8; ++e)
            a1[e] = (__bf16)swishf(fmaf(u, w1v[8 + e], b1v[8 + e]));

        // layer 2 on the matrix pipe: 4 v-tiles x K=64
        f32x4 acc[4];
#pragma unroll
        for (int vt = 0; vt < 4; ++vt) {
            acc[vt] = (f32x4){0.f, 0.f, 0.f, 0.f};
            acc[vt] = __builtin_amdgcn_mfma_f32_16x16x32_bf16(a0, wfrag[vt][0], acc[vt], 0, 0, 0);
            acc[vt] = __builtin_amdgcn_mfma_f32_16x16x32_bf16(a1, wfrag[vt][1], acc[vt], 0, 0, 0);
        }

        // layer 3: swish + w3 dot, reduce across the 16 v-lanes
        float part[4];
#pragma unroll
        for (int g = 0; g < 4; ++g) {
            float p = 0.0f;
#pragma unroll
            for (int vt = 0; vt < 4; ++vt)
                p = fmaf(swishf(acc[vt][g] + b2v[vt]), w3v[vt], p);
            part[g] = p;
        }
#pragma unroll
        for (int g = 0; g < 4; ++g) {
            part[g] += __shfl_xor(part[g], 1);
            part[g] += __shfl_xor(part[g], 2);
            part[g] += __shfl_xor(part[g], 4);
            part[g] += __shfl_xor(part[g], 8);
        }

        if (lr == 0) {
            const int row = bb + lg * 4;
            if (MODE == 0) {
                *reinterpret_cast<float4*>(dst + row) =
                    make_float4(part[0] + b3v, part[1] + b3v,
                                part[2] + b3v, part[3] + b3v);
            } else if (MODE == 1) {
#pragma unroll
                for (int g = 0; g < 4; ++g)
                    out[((size_t)(row + g) * MT + m) * 2 + br] = part[g] + b3v;
            } else {
#pragma unroll
                for (int g = 0; g < 4; ++g)
                    out[(size_t)(row + g) * MT + m] = part[g] + b3v;
            }
        }
    }
}

// ws[NBR][256][4096] -> out. NBR=2: [b][m][re,im]; NBR=1: transpose to [b][m].
// (Verbatim from the round-2/5/6 PASS.)
template<int NBR>
__global__ __launch_bounds__(256) void rmat_interleave(
    const float* __restrict__ ws, float* __restrict__ out)
{
    __shared__ float tile[NBR][32][64 + 1];
    const int bt = blockIdx.x & 63;
    const int mt = blockIdx.x >> 6;
    const int b0 = bt * 64, m0 = mt * 32;

    for (int i = threadIdx.x; i < NBR * 32 * 64; i += 256) {
        const int brx = i >> 11;           // 0 when NBR==1
        const int r   = (i >> 6) & 31;
        const int c   = i & 63;
        tile[brx][r][c] = ws[(size_t)(brx * MT + m0 + r) * BSZ + b0 + c];
    }
    __syncthreads();

    const int tb   = threadIdx.x >> 2;
    const int part = threadIdx.x & 3;
    const int b = b0 + tb;
    if (NBR == 2) {
        float2* __restrict__ dstp =
            reinterpret_cast<float2*>(out) + (size_t)b * MT + m0 + part * 8;
#pragma unroll
        for (int k = 0; k < 8; ++k) {
            const int mm = part * 8 + k;
            dstp[k] = make_float2(tile[0][mm][tb], tile[1][mm][tb]);
        }
    } else {
        float* __restrict__ dstp = out + (size_t)b * MT + m0 + part * 8;
#pragma unroll
        for (int k = 0; k < 8; ++k)
            dstp[k] = tile[0][part * 8 + k][tb];
    }
}

extern "C" void kernel_launch(void* const* d_in, const int* in_sizes, int n_in,
                              void* d_out, int out_size, void* d_ws, size_t ws_size,
                              hipStream_t stream) {
    const float* U   = (const float*)d_in[0];
    const float* W1r = (const float*)d_in[1];
    const float* b1r = (const float*)d_in[2];
    const float* W2r = (const float*)d_in[3];
    const float* b2r = (const float*)d_in[4];
    const float* W3r = (const float*)d_in[5];
    const float* b3r = (const float*)d_in[6];
    const float* W1i = (const float*)d_in[7];
    const float* b1i = (const float*)d_in[8];
    const float* W2i = (const float*)d_in[9];
    const float* b2i = (const float*)d_in[10];
    const float* W3i = (const float*)d_in[11];
    const float* b3i = (const float*)d_in[12];
    float* out = (float*)d_out;
    float* ws  = (float*)d_ws;

    const dim3 grid(MT * NCH), block(256);
    const size_t plane = (size_t)MT * BSZ;   // floats per branch

    if (out_size >= (int)(2 * plane)) {
        // d_out = [B][M] of (re,im) float pairs
        if (ws_size >= 2 * plane * sizeof(float)) {
            rmat_mlp_mfma<0><<<grid, block, 0, stream>>>(U, W1r, b1r, W2r, b2r, W3r, b3r, ws, 0);
            rmat_mlp_mfma<0><<<grid, block, 0, stream>>>(U, W1i, b1i, W2i, b2i, W3i, b3i, ws + plane, 1);
            rmat_interleave<2><<<dim3(512), block, 0, stream>>>(ws, out);
        } else {
            rmat_mlp_mfma<1><<<grid, block, 0, stream>>>(U, W1r, b1r, W2r, b2r, W3r, b3r, out, 0);
            rmat_mlp_mfma<1><<<grid, block, 0, stream>>>(U, W1i, b1i, W2i, b2i, W3i, b3i, out, 1);
        }
    } else {
        // d_out holds B*M float32 -> real branch only (harness drops imag)
        if (ws_size >= plane * sizeof(float)) {
            rmat_mlp_mfma<0><<<grid, block, 0, stream>>>(U, W1r, b1r, W2r, b2r, W3r, b3r, ws, 0);
            rmat_interleave<1><<<dim3(512), block, 0, stream>>>(ws, out);
        } else {
            rmat_mlp_mfma<2><<<grid, block, 0, stream>>>(U, W1r, b1r, W2r, b2r, W3r, b3r, out, 0);
        }
    }
}

// Round 9
// 53.057 us; speedup vs baseline: 3.3008x; 1.0283x over previous
//
#include <hip/hip_runtime.h>
#include <cstdint>
#include <cstddef>

#define WD  50
#define MT  256
#define BSZ 4096
#define NCH 4                  // batch chunks per (m,branch): 1024 blocks
#define BCH (BSZ / NCH)        // 1024 rows per block
#define ITERS (BCH / 4 / 16)   // 16 row-groups of 16 per wave

typedef __bf16 bf16x8 __attribute__((ext_vector_type(8)));
typedef float  f32x4  __attribute__((ext_vector_type(4)));

__device__ __forceinline__ float swishf(float x) {
    // x * sigmoid(x) via v_rcp_f32 (rel err ~1e-5, noise vs bf16 rounding)
    return x * __builtin_amdgcn_rcpf(1.0f + __expf(-x));
}

// Fused 1->50->50->1 MLP, layer-2 on bf16 MFMA (16x16x32), one branch.
// Block = (m, batch-chunk). 4 waves; TWO independent 16-row streams per
// loop iteration (round-8 lesson: latency-bound inside the wave, not
// occupancy-bound -> fill the swish/shuffle latency with a second stream).
// A (h1):  lane l -> row b=l&15,  k=(l>>4)*8+e  (computed in-register)
// B (W2^T):lane l -> col v=l&15,  k=(l>>4)*8+e  (static, 8 frags)
// D:       col v=l&15, row=(l>>4)*4+g           [m89-verified]
// Round-7 lesson: keep __launch_bounds__(256,4) — the (256,8) cap spilled.
// MODE 0: out[m*BSZ + b]   MODE 1: out[(b*MT+m)*2+br]   MODE 2: out[b*MT+m]
template<int MODE>
__global__ __launch_bounds__(256, 4) void rmat_mlp_mfma(
    const float* __restrict__ U,
    const float* __restrict__ W1, const float* __restrict__ B1,
    const float* __restrict__ W2, const float* __restrict__ B2,
    const float* __restrict__ W3, const float* __restrict__ B3,
    float* __restrict__ out, int br)
{
    const int m  = blockIdx.x >> 2;        // 0..255
    const int ch = blockIdx.x & 3;         // 0..3

    const float* __restrict__ w1 = W1 + m * WD;
    const float* __restrict__ b1 = B1 + m * WD;
    const float* __restrict__ w2 = W2 + (size_t)m * WD * WD;
    const float* __restrict__ b2 = B2 + m * WD;
    const float* __restrict__ w3 = W3 + m * WD;
    const float  b3v = B3[m];

    const int lane = threadIdx.x & 63;
    const int wid  = threadIdx.x >> 6;
    const int lr   = lane & 15;            // A-row / D-col(v)
    const int lg   = lane >> 4;            // k-group / D-row-group

    // ---- static per-lane state (one-time prologue) ----
    bf16x8 wfrag[4][2];                    // W2^T: 4 v-tiles x 2 k-tiles
#pragma unroll
    for (int vt = 0; vt < 4; ++vt) {
        const int v = vt * 16 + lr;
#pragma unroll
        for (int kt = 0; kt < 2; ++kt)
#pragma unroll
            for (int e = 0; e < 8; ++e) {
                const int k = kt * 32 + lg * 8 + e;
                const float w = (v < WD && k < WD) ? w2[v * WD + k] : 0.0f;
                wfrag[vt][kt][e] = (__bf16)w;
            }
    }
    float w1v[16], b1v[16];                // this lane's 16 k slots
#pragma unroll
    for (int kt = 0; kt < 2; ++kt)
#pragma unroll
        for (int e = 0; e < 8; ++e) {
            const int k = kt * 32 + lg * 8 + e;
            w1v[kt * 8 + e] = (k < WD) ? w1[k] : 0.0f;
            b1v[kt * 8 + e] = (k < WD) ? b1[k] : 0.0f;
        }
    float b2v[4], w3v[4];                  // this lane's v per v-tile
#pragma unroll
    for (int vt = 0; vt < 4; ++vt) {
        const int v = vt * 16 + lr;
        b2v[vt] = (v < WD) ? b2[v] : 0.0f;
        w3v[vt] = (v < WD) ? w3[v] : 0.0f;
    }

    float* __restrict__ dst = out + (size_t)m * BSZ;   // MODE 0 base
    const int b0 = ch * BCH + wid * (BCH / 4);         // wave's 256-row slice

    // one 16-row stream: layer1 -> MFMA -> layer3 -> reduce -> store
    auto stream16 = [&](int bb, float u) {
        bf16x8 a0, a1;
#pragma unroll
        for (int e = 0; e < 8; ++e)
            a0[e] = (__bf16)swishf(fmaf(u, w1v[e], b1v[e]));
#pragma unroll
        for (int e = 0; e < 8; ++e)
            a1[e] = (__bf16)swishf(fmaf(u, w1v[8 + e], b1v[8 + e]));

        f32x4 acc[4];
#pragma unroll
        for (int vt = 0; vt < 4; ++vt) {
            acc[vt] = (f32x4){0.f, 0.f, 0.f, 0.f};
            acc[vt] = __builtin_amdgcn_mfma_f32_16x16x32_bf16(a0, wfrag[vt][0], acc[vt], 0, 0, 0);
            acc[vt] = __builtin_amdgcn_mfma_f32_16x16x32_bf16(a1, wfrag[vt][1], acc[vt], 0, 0, 0);
        }

        float part[4];
#pragma unroll
        for (int g = 0; g < 4; ++g) {
            float p = 0.0f;
#pragma unroll
            for (int vt = 0; vt < 4; ++vt)
                p = fmaf(swishf(acc[vt][g] + b2v[vt]), w3v[vt], p);
            part[g] = p;
        }
#pragma unroll
        for (int g = 0; g < 4; ++g) {
            part[g] += __shfl_xor(part[g], 1);
            part[g] += __shfl_xor(part[g], 2);
            part[g] += __shfl_xor(part[g], 4);
            part[g] += __shfl_xor(part[g], 8);
        }

        if (lr == 0) {
            const int row = bb + lg * 4;
            if (MODE == 0) {
                *reinterpret_cast<float4*>(dst + row) =
                    make_float4(part[0] + b3v, part[1] + b3v,
                                part[2] + b3v, part[3] + b3v);
            } else if (MODE == 1) {
#pragma unroll
                for (int g = 0; g < 4; ++g)
                    out[((size_t)(row + g) * MT + m) * 2 + br] = part[g] + b3v;
            } else {
#pragma unroll
                for (int g = 0; g < 4; ++g)
                    out[(size_t)(row + g) * MT + m] = part[g] + b3v;
            }
        }
    };

#pragma unroll 1
    for (int it = 0; it < ITERS; it += 2) {
        const int bbA = b0 + it * 16;
        const int bbB = bbA + 16;
        const float uA = U[bbA + lr];      // both loads issued up front
        const float uB = U[bbB + lr];
        stream16(bbA, uA);                 // one basic block: scheduler
        stream16(bbB, uB);                 // interleaves the two streams
    }
}

// ws[NBR][256][4096] -> out. NBR=2: [b][m][re,im]; NBR=1: transpose to [b][m].
// (Verbatim from the round-2/5/6 PASS.)
template<int NBR>
__global__ __launch_bounds__(256) void rmat_interleave(
    const float* __restrict__ ws, float* __restrict__ out)
{
    __shared__ float tile[NBR][32][64 + 1];
    const int bt = blockIdx.x & 63;
    const int mt = blockIdx.x >> 6;
    const int b0 = bt * 64, m0 = mt * 32;

    for (int i = threadIdx.x; i < NBR * 32 * 64; i += 256) {
        const int brx = i >> 11;           // 0 when NBR==1
        const int r   = (i >> 6) & 31;
        const int c   = i & 63;
        tile[brx][r][c] = ws[(size_t)(brx * MT + m0 + r) * BSZ + b0 + c];
    }
    __syncthreads();

    const int tb   = threadIdx.x >> 2;
    const int part = threadIdx.x & 3;
    const int b = b0 + tb;
    if (NBR == 2) {
        float2* __restrict__ dstp =
            reinterpret_cast<float2*>(out) + (size_t)b * MT + m0 + part * 8;
#pragma unroll
        for (int k = 0; k < 8; ++k) {
            const int mm = part * 8 + k;
            dstp[k] = make_float2(tile[0][mm][tb], tile[1][mm][tb]);
        }
    } else {
        float* __restrict__ dstp = out + (size_t)b * MT + m0 + part * 8;
#pragma unroll
        for (int k = 0; k < 8; ++k)
            dstp[k] = tile[0][part * 8 + k][tb];
    }
}

extern "C" void kernel_launch(void* const* d_in, const int* in_sizes, int n_in,
                              void* d_out, int out_size, void* d_ws, size_t ws_size,
                              hipStream_t stream) {
    const float* U   = (const float*)d_in[0];
    const float* W1r = (const float*)d_in[1];
    const float* b1r = (const float*)d_in[2];
    const float* W2r = (const float*)d_in[3];
    const float* b2r = (const float*)d_in[4];
    const float* W3r = (const float*)d_in[5];
    const float* b3r = (const float*)d_in[6];
    const float* W1i = (const float*)d_in[7];
    const float* b1i = (const float*)d_in[8];
    const float* W2i = (const float*)d_in[9];
    const float* b2i = (const float*)d_in[10];
    const float* W3i = (const float*)d_in[11];
    const float* b3i = (const float*)d_in[12];
    float* out = (float*)d_out;
    float* ws  = (float*)d_ws;

    const dim3 grid(MT * NCH), block(256);
    const size_t plane = (size_t)MT * BSZ;   // floats per branch

    if (out_size >= (int)(2 * plane)) {
        // d_out = [B][M] of (re,im) float pairs
        if (ws_size >= 2 * plane * sizeof(float)) {
            rmat_mlp_mfma<0><<<grid, block, 0, stream>>>(U, W1r, b1r, W2r, b2r, W3r, b3r, ws, 0);
            rmat_mlp_mfma<0><<<grid, block, 0, stream>>>(U, W1i, b1i, W2i, b2i, W3i, b3i, ws + plane, 1);
            rmat_interleave<2><<<dim3(512), block, 0, stream>>>(ws, out);
        } else {
            rmat_mlp_mfma<1><<<grid, block, 0, stream>>>(U, W1r, b1r, W2r, b2r, W3r, b3r, out, 0);
            rmat_mlp_mfma<1><<<grid, block, 0, stream>>>(U, W1i, b1i, W2i, b2i, W3i, b3i, out, 1);
        }
    } else {
        // d_out holds B*M float32 -> real branch only (harness drops imag)
        if (ws_size >= plane * sizeof(float)) {
            rmat_mlp_mfma<0><<<grid, block, 0, stream>>>(U, W1r, b1r, W2r, b2r, W3r, b3r, ws, 0);
            rmat_interleave<1><<<dim3(512), block, 0, stream>>>(ws, out);
        } else {
            rmat_mlp_mfma<2><<<grid, block, 0, stream>>>(U, W1r, b1r, W2r, b2r, W3r, b3r, out, 0);
        }
    }
}

// Round 10
// 50.812 us; speedup vs baseline: 3.4467x; 1.0442x over previous
//
#include <hip/hip_runtime.h>
#include <cstdint>
#include <cstddef>

#define WD  50
#define MT  256
#define BSZ 4096
#define NCH 4                  // batch chunks per (m,branch): 1024 blocks
#define BCH (BSZ / NCH)        // 1024 rows per block
#define ITERS (BCH / 4 / 16)   // 16 iters: per wave 256 rows, 16/iter

typedef __bf16 bf16x8 __attribute__((ext_vector_type(8)));
typedef float  f32x4  __attribute__((ext_vector_type(4)));

__device__ __forceinline__ float swishf(float x) {
    // x * sigmoid(x) via v_rcp_f32 (rel err ~1e-5, noise vs bf16 rounding)
    return x * __builtin_amdgcn_rcpf(1.0f + __expf(-x));
}

// Fused 1->50->50->1 MLP, layer-2 on bf16 MFMA (16x16x32), one branch.
// TRANSPOSED orientation (round-10): mfma(A=W2, B=h1) so D has
// col = batch = l&15, row = v = vt*16 + (l>>4)*4+g  [m89 C/D layout].
//   - layer-3 reduce: over lg only -> 2 shfl_xor steps (was 4)
//   - k-slot remap k = half*32 + e*4 + lg: pad k>=52 lands in wave-uniform
//     slots e=5..7 of half1 -> layer-1 swish 16->13 per lane (a1[5..7]=0)
//   - b2 folded into MFMA C-in; u prefetched one iter ahead
// Round-7 lesson: no tight wave cap; (256,3) gives ~170 VGPR, no spill.
// MODE 0: out[m*BSZ + b]   MODE 1: out[(b*MT+m)*2+br]   MODE 2: out[b*MT+m]
template<int MODE>
__global__ __launch_bounds__(256, 3) void rmat_mlp_mfma(
    const float* __restrict__ U,
    const float* __restrict__ W1, const float* __restrict__ B1,
    const float* __restrict__ W2, const float* __restrict__ B2,
    const float* __restrict__ W3, const float* __restrict__ B3,
    float* __restrict__ out, int br)
{
    const int m  = blockIdx.x >> 2;        // 0..255
    const int ch = blockIdx.x & 3;         // 0..3

    const float* __restrict__ w1 = W1 + m * WD;
    const float* __restrict__ b1 = B1 + m * WD;
    const float* __restrict__ w2 = W2 + (size_t)m * WD * WD;
    const float* __restrict__ b2 = B2 + m * WD;
    const float* __restrict__ w3 = W3 + m * WD;
    const float  b3v = B3[m];

    const int lane = threadIdx.x & 63;
    const int wid  = threadIdx.x >> 6;
    const int lr   = lane & 15;            // A-row (v mod 16) / D-col (batch)
    const int lg   = lane >> 4;            // k sub-slot / D-row group

    // ---- static per-lane state (one-time prologue) ----
    // logical k for slot (half, lg, e) = half*32 + e*4 + lg  (bijection)
    bf16x8 wfrag[4][2];                    // A-operand: W2, 4 v-tiles x 2 k-halves
#pragma unroll
    for (int vt = 0; vt < 4; ++vt) {
        const int v = vt * 16 + lr;
#pragma unroll
        for (int kt = 0; kt < 2; ++kt)
#pragma unroll
            for (int e = 0; e < 8; ++e) {
                const int k = kt * 32 + e * 4 + lg;
                const float w = (v < WD && k < WD) ? w2[v * WD + k] : 0.0f;
                wfrag[vt][kt][e] = (__bf16)w;
            }
    }
    // layer-1 weights: half0 slots e=0..7 (k=e*4+lg, all <32), half1 e=0..4
    float w1v[13], b1v[13];
#pragma unroll
    for (int e = 0; e < 8; ++e) {
        const int k = e * 4 + lg;
        w1v[e] = w1[k];  b1v[e] = b1[k];
    }
#pragma unroll
    for (int e = 0; e < 5; ++e) {
        const int k = 32 + e * 4 + lg;
        w1v[8 + e] = (k < WD) ? w1[k] : 0.0f;
        b1v[8 + e] = (k < WD) ? b1[k] : 0.0f;
    }
    // layer-3: v = vt*16 + lg*4 + g per (vt,g)
    float b2v[4][4], w3v[4][4];
#pragma unroll
    for (int vt = 0; vt < 4; ++vt)
#pragma unroll
        for (int g = 0; g < 4; ++g) {
            const int v = vt * 16 + lg * 4 + g;
            b2v[vt][g] = (v < WD) ? b2[v] : 0.0f;
            w3v[vt][g] = (v < WD) ? w3[v] : 0.0f;
        }

    float* __restrict__ dst = out + (size_t)m * BSZ;   // MODE 0 base
    const int b0 = ch * BCH + wid * (BCH / 4);         // wave's 256-row slice

    float u = U[b0 + lr];                  // prefetched first u
#pragma unroll 1
    for (int it = 0; it < ITERS; ++it) {
        const int bb = b0 + it * 16;
        const float u_next = (it + 1 < ITERS) ? U[bb + 16 + lr] : 0.0f;

        // layer 1 -> B fragments (batch col = lr); pad slots are constant 0
        bf16x8 a0, a1 = {};
#pragma unroll
        for (int e = 0; e < 8; ++e)
            a0[e] = (__bf16)swishf(fmaf(u, w1v[e], b1v[e]));
#pragma unroll
        for (int e = 0; e < 5; ++e)
            a1[e] = (__bf16)swishf(fmaf(u, w1v[8 + e], b1v[8 + e]));

        // layer 2: D[v][batch], bias b2 enters as C-in
        f32x4 acc[4];
#pragma unroll
        for (int vt = 0; vt < 4; ++vt) {
            acc[vt] = (f32x4){b2v[vt][0], b2v[vt][1], b2v[vt][2], b2v[vt][3]};
            acc[vt] = __builtin_amdgcn_mfma_f32_16x16x32_bf16(wfrag[vt][0], a0, acc[vt], 0, 0, 0);
            acc[vt] = __builtin_amdgcn_mfma_f32_16x16x32_bf16(wfrag[vt][1], a1, acc[vt], 0, 0, 0);
        }

        // layer 3: 16 in-lane swish+dot, then 2-step reduce over lg lanes
        float p0 = 0.0f, p1 = 0.0f, p2 = 0.0f, p3 = 0.0f;
#pragma unroll
        for (int g = 0; g < 4; ++g) {
            p0 = fmaf(w3v[0][g], swishf(acc[0][g]), p0);
            p1 = fmaf(w3v[1][g], swishf(acc[1][g]), p1);
            p2 = fmaf(w3v[2][g], swishf(acc[2][g]), p2);
            p3 = fmaf(w3v[3][g], swishf(acc[3][g]), p3);
        }
        float p = (p0 + p1) + (p2 + p3);
        p += __shfl_xor(p, 16);
        p += __shfl_xor(p, 32);

        u = u_next;

        if (lane < 16) {                    // lg==0: one result per batch col
            const int row = bb + lane;
            if (MODE == 0)      dst[row] = p + b3v;            // 64B/wave, coalesced
            else if (MODE == 1) out[((size_t)row * MT + m) * 2 + br] = p + b3v;
            else                out[(size_t)row * MT + m] = p + b3v;
        }
    }
}

// ws[NBR][256][4096] -> out. NBR=2: [b][m][re,im]; NBR=1: transpose to [b][m].
// (Verbatim from the round-2/5/6 PASS.)
template<int NBR>
__global__ __launch_bounds__(256) void rmat_interleave(
    const float* __restrict__ ws, float* __restrict__ out)
{
    __shared__ float tile[NBR][32][64 + 1];
    const int bt = blockIdx.x & 63;
    const int mt = blockIdx.x >> 6;
    const int b0 = bt * 64, m0 = mt * 32;

    for (int i = threadIdx.x; i < NBR * 32 * 64; i += 256) {
        const int brx = i >> 11;           // 0 when NBR==1
        const int r   = (i >> 6) & 31;
        const int c   = i & 63;
        tile[brx][r][c] = ws[(size_t)(brx * MT + m0 + r) * BSZ + b0 + c];
    }
    __syncthreads();

    const int tb   = threadIdx.x >> 2;
    const int part = threadIdx.x & 3;
    const int b = b0 + tb;
    if (NBR == 2) {
        float2* __restrict__ dstp =
            reinterpret_cast<float2*>(out) + (size_t)b * MT + m0 + part * 8;
#pragma unroll
        for (int k = 0; k < 8; ++k) {
            const int mm = part * 8 + k;
            dstp[k] = make_float2(tile[0][mm][tb], tile[1][mm][tb]);
        }
    } else {
        float* __restrict__ dstp = out + (size_t)b * MT + m0 + part * 8;
#pragma unroll
        for (int k = 0; k < 8; ++k)
            dstp[k] = tile[0][part * 8 + k][tb];
    }
}

extern "C" void kernel_launch(void* const* d_in, const int* in_sizes, int n_in,
                              void* d_out, int out_size, void* d_ws, size_t ws_size,
                              hipStream_t stream) {
    const float* U   = (const float*)d_in[0];
    const float* W1r = (const float*)d_in[1];
    const float* b1r = (const float*)d_in[2];
    const float* W2r = (const float*)d_in[3];
    const float* b2r = (const float*)d_in[4];
    const float* W3r = (const float*)d_in[5];
    const float* b3r = (const float*)d_in[6];
    const float* W1i = (const float*)d_in[7];
    const float* b1i = (const float*)d_in[8];
    const float* W2i = (const float*)d_in[9];
    const float* b2i = (const float*)d_in[10];
    const float* W3i = (const float*)d_in[11];
    const float* b3i = (const float*)d_in[12];
    float* out = (float*)d_out;
    float* ws  = (float*)d_ws;

    const dim3 grid(MT * NCH), block(256);
    const size_t plane = (size_t)MT * BSZ;   // floats per branch

    if (out_size >= (int)(2 * plane)) {
        // d_out = [B][M] of (re,im) float pairs
        if (ws_size >= 2 * plane * sizeof(float)) {
            rmat_mlp_mfma<0><<<grid, block, 0, stream>>>(U, W1r, b1r, W2r, b2r, W3r, b3r, ws, 0);
            rmat_mlp_mfma<0><<<grid, block, 0, stream>>>(U, W1i, b1i, W2i, b2i, W3i, b3i, ws + plane, 1);
            rmat_interleave<2><<<dim3(512), block, 0, stream>>>(ws, out);
        } else {
            rmat_mlp_mfma<1><<<grid, block, 0, stream>>>(U, W1r, b1r, W2r, b2r, W3r, b3r, out, 0);
            rmat_mlp_mfma<1><<<grid, block, 0, stream>>>(U, W1i, b1i, W2i, b2i, W3i, b3i, out, 1);
        }
    } else {
        // d_out holds B*M float32 -> real branch only (harness drops imag)
        if (ws_size >= plane * sizeof(float)) {
            rmat_mlp_mfma<0><<<grid, block, 0, stream>>>(U, W1r, b1r, W2r, b2r, W3r, b3r, ws, 0);
            rmat_interleave<1><<<dim3(512), block, 0, stream>>>(ws, out);
        } else {
            rmat_mlp_mfma<2><<<grid, block, 0, stream>>>(U, W1r, b1r, W2r, b2r, W3r, b3r, out, 0);
        }
    }
}

// Round 11
// 50.808 us; speedup vs baseline: 3.4469x; 1.0001x over previous
//
#include <hip/hip_runtime.h>
#include <cstdint>
#include <cstddef>

#define WD  50
#define MT  256
#define BSZ 4096
#define NCH 4                  // batch chunks per (m,branch): 1024 blocks
#define BCH (BSZ / NCH)        // 1024 rows per block
#define ITERS (BCH / 4 / 16)   // 16 iters: per wave 256 rows, 16/iter

typedef __bf16 bf16x8 __attribute__((ext_vector_type(8)));
typedef float  f32x4  __attribute__((ext_vector_type(4)));

#define LOG2E 1.44269504088896340736f

__device__ __forceinline__ float swishf(float x) {
    // x * sigmoid(x) = x * rcp(1 + 2^(-x*log2e))
    // Round-11: bare v_exp_f32 via __builtin_amdgcn_exp2f — __expf without
    // fast-math lowers to an ocml range-reduced sequence (~10 VALU ops);
    // this is exactly 5 instructions (mul, exp2, add, rcp, mul).
    // x->-inf: 2^t=inf, rcp=0, y=0 ✓ ; x->+inf: 2^t=0, rcp(1)=1, y=x ✓
    return x * __builtin_amdgcn_rcpf(1.0f + __builtin_amdgcn_exp2f(-LOG2E * x));
}

// Fused 1->50->50->1 MLP, layer-2 on bf16 MFMA (16x16x32), one branch.
// TRANSPOSED orientation (round-10): mfma(A=W2, B=h1) so D has
// col = batch = l&15, row = v = vt*16 + (l>>4)*4+g  [m89 C/D layout].
//   - layer-3 reduce: over lg only -> 2 shfl_xor steps (was 4)
//   - k-slot remap k = half*32 + e*4 + lg: pad k>=52 lands in wave-uniform
//     slots e=5..7 of half1 -> layer-1 swish 16->13 per lane (a1[5..7]=0)
//   - b2 folded into MFMA C-in; u prefetched one iter ahead
// Round-7 lesson: no tight wave cap; (256,3) gives ~170 VGPR, no spill.
// MODE 0: out[m*BSZ + b]   MODE 1: out[(b*MT+m)*2+br]   MODE 2: out[b*MT+m]
template<int MODE>
__global__ __launch_bounds__(256, 3) void rmat_mlp_mfma(
    const float* __restrict__ U,
    const float* __restrict__ W1, const float* __restrict__ B1,
    const float* __restrict__ W2, const float* __restrict__ B2,
    const float* __restrict__ W3, const float* __restrict__ B3,
    float* __restrict__ out, int br)
{
    const int m  = blockIdx.x >> 2;        // 0..255
    const int ch = blockIdx.x & 3;         // 0..3

    const float* __restrict__ w1 = W1 + m * WD;
    const float* __restrict__ b1 = B1 + m * WD;
    const float* __restrict__ w2 = W2 + (size_t)m * WD * WD;
    const float* __restrict__ b2 = B2 + m * WD;
    const float* __restrict__ w3 = W3 + m * WD;
    const float  b3v = B3[m];

    const int lane = threadIdx.x & 63;
    const int wid  = threadIdx.x >> 6;
    const int lr   = lane & 15;            // A-row (v mod 16) / D-col (batch)
    const int lg   = lane >> 4;            // k sub-slot / D-row group

    // ---- static per-lane state (one-time prologue) ----
    // logical k for slot (half, lg, e) = half*32 + e*4 + lg  (bijection)
    bf16x8 wfrag[4][2];                    // A-operand: W2, 4 v-tiles x 2 k-halves
#pragma unroll
    for (int vt = 0; vt < 4; ++vt) {
        const int v = vt * 16 + lr;
#pragma unroll
        for (int kt = 0; kt < 2; ++kt)
#pragma unroll
            for (int e = 0; e < 8; ++e) {
                const int k = kt * 32 + e * 4 + lg;
                const float w = (v < WD && k < WD) ? w2[v * WD + k] : 0.0f;
                wfrag[vt][kt][e] = (__bf16)w;
            }
    }
    // layer-1 weights: half0 slots e=0..7 (k=e*4+lg, all <32), half1 e=0..4
    float w1v[13], b1v[13];
#pragma unroll
    for (int e = 0; e < 8; ++e) {
        const int k = e * 4 + lg;
        w1v[e] = w1[k];  b1v[e] = b1[k];
    }
#pragma unroll
    for (int e = 0; e < 5; ++e) {
        const int k = 32 + e * 4 + lg;
        w1v[8 + e] = (k < WD) ? w1[k] : 0.0f;
        b1v[8 + e] = (k < WD) ? b1[k] : 0.0f;
    }
    // layer-3: v = vt*16 + lg*4 + g per (vt,g)
    float b2v[4][4], w3v[4][4];
#pragma unroll
    for (int vt = 0; vt < 4; ++vt)
#pragma unroll
        for (int g = 0; g < 4; ++g) {
            const int v = vt * 16 + lg * 4 + g;
            b2v[vt][g] = (v < WD) ? b2[v] : 0.0f;
            w3v[vt][g] = (v < WD) ? w3[v] : 0.0f;
        }

    float* __restrict__ dst = out + (size_t)m * BSZ;   // MODE 0 base
    const int b0 = ch * BCH + wid * (BCH / 4);         // wave's 256-row slice

    float u = U[b0 + lr];                  // prefetched first u
#pragma unroll 1
    for (int it = 0; it < ITERS; ++it) {
        const int bb = b0 + it * 16;
        const float u_next = (it + 1 < ITERS) ? U[bb + 16 + lr] : 0.0f;

        // layer 1 -> B fragments (batch col = lr); pad slots are constant 0
        bf16x8 a0, a1 = {};
#pragma unroll
        for (int e = 0; e < 8; ++e)
            a0[e] = (__bf16)swishf(fmaf(u, w1v[e], b1v[e]));
#pragma unroll
        for (int e = 0; e < 5; ++e)
            a1[e] = (__bf16)swishf(fmaf(u, w1v[8 + e], b1v[8 + e]));

        // layer 2: D[v][batch], bias b2 enters as C-in
        f32x4 acc[4];
#pragma unroll
        for (int vt = 0; vt < 4; ++vt) {
            acc[vt] = (f32x4){b2v[vt][0], b2v[vt][1], b2v[vt][2], b2v[vt][3]};
            acc[vt] = __builtin_amdgcn_mfma_f32_16x16x32_bf16(wfrag[vt][0], a0, acc[vt], 0, 0, 0);
            acc[vt] = __builtin_amdgcn_mfma_f32_16x16x32_bf16(wfrag[vt][1], a1, acc[vt], 0, 0, 0);
        }

        // layer 3: 16 in-lane swish+dot, then 2-step reduce over lg lanes
        float p0 = 0.0f, p1 = 0.0f, p2 = 0.0f, p3 = 0.0f;
#pragma unroll
        for (int g = 0; g < 4; ++g) {
            p0 = fmaf(w3v[0][g], swishf(acc[0][g]), p0);
            p1 = fmaf(w3v[1][g], swishf(acc[1][g]), p1);
            p2 = fmaf(w3v[2][g], swishf(acc[2][g]), p2);
            p3 = fmaf(w3v[3][g], swishf(acc[3][g]), p3);
        }
        float p = (p0 + p1) + (p2 + p3);
        p += __shfl_xor(p, 16);
        p += __shfl_xor(p, 32);

        u = u_next;

        if (lane < 16) {                    // lg==0: one result per batch col
            const int row = bb + lane;
            if (MODE == 0)      dst[row] = p + b3v;            // 64B/wave, coalesced
            else if (MODE == 1) out[((size_t)row * MT + m) * 2 + br] = p + b3v;
            else                out[(size_t)row * MT + m] = p + b3v;
        }
    }
}

// ws[NBR][256][4096] -> out. NBR=2: [b][m][re,im]; NBR=1: transpose to [b][m].
// (Verbatim from the round-2/5/6 PASS.)
template<int NBR>
__global__ __launch_bounds__(256) void rmat_interleave(
    const float* __restrict__ ws, float* __restrict__ out)
{
    __shared__ float tile[NBR][32][64 + 1];
    const int bt = blockIdx.x & 63;
    const int mt = blockIdx.x >> 6;
    const int b0 = bt * 64, m0 = mt * 32;

    for (int i = threadIdx.x; i < NBR * 32 * 64; i += 256) {
        const int brx = i >> 11;           // 0 when NBR==1
        const int r   = (i >> 6) & 31;
        const int c   = i & 63;
        tile[brx][r][c] = ws[(size_t)(brx * MT + m0 + r) * BSZ + b0 + c];
    }
    __syncthreads();

    const int tb   = threadIdx.x >> 2;
    const int part = threadIdx.x & 3;
    const int b = b0 + tb;
    if (NBR == 2) {
        float2* __restrict__ dstp =
            reinterpret_cast<float2*>(out) + (size_t)b * MT + m0 + part * 8;
#pragma unroll
        for (int k = 0; k < 8; ++k) {
            const int mm = part * 8 + k;
            dstp[k] = make_float2(tile[0][mm][tb], tile[1][mm][tb]);
        }
    } else {
        float* __restrict__ dstp = out + (size_t)b * MT + m0 + part * 8;
#pragma unroll
        for (int k = 0; k < 8; ++k)
            dstp[k] = tile[0][part * 8 + k][tb];
    }
}

extern "C" void kernel_launch(void* const* d_in, const int* in_sizes, int n_in,
                              void* d_out, int out_size, void* d_ws, size_t ws_size,
                              hipStream_t stream) {
    const float* U   = (const float*)d_in[0];
    const float* W1r = (const float*)d_in[1];
    const float* b1r = (const float*)d_in[2];
    const float* W2r = (const float*)d_in[3];
    const float* b2r = (const float*)d_in[4];
    const float* W3r = (const float*)d_in[5];
    const float* b3r = (const float*)d_in[6];
    const float* W1i = (const float*)d_in[7];
    const float* b1i = (const float*)d_in[8];
    const float* W2i = (const float*)d_in[9];
    const float* b2i = (const float*)d_in[10];
    const float* W3i = (const float*)d_in[11];
    const float* b3i = (const float*)d_in[12];
    float* out = (float*)d_out;
    float* ws  = (float*)d_ws;

    const dim3 grid(MT * NCH), block(256);
    const size_t plane = (size_t)MT * BSZ;   // floats per branch

    if (out_size >= (int)(2 * plane)) {
        // d_out = [B][M] of (re,im) float pairs
        if (ws_size >= 2 * plane * sizeof(float)) {
            rmat_mlp_mfma<0><<<grid, block, 0, stream>>>(U, W1r, b1r, W2r, b2r, W3r, b3r, ws, 0);
            rmat_mlp_mfma<0><<<grid, block, 0, stream>>>(U, W1i, b1i, W2i, b2i, W3i, b3i, ws + plane, 1);
            rmat_interleave<2><<<dim3(512), block, 0, stream>>>(ws, out);
        } else {
            rmat_mlp_mfma<1><<<grid, block, 0, stream>>>(U, W1r, b1r, W2r, b2r, W3r, b3r, out, 0);
            rmat_mlp_mfma<1><<<grid, block, 0, stream>>>(U, W1i, b1i, W2i, b2i, W3i, b3i, out, 1);
        }
    } else {
        // d_out holds B*M float32 -> real branch only (harness drops imag)
        if (ws_size >= plane * sizeof(float)) {
            rmat_mlp_mfma<0><<<grid, block, 0, stream>>>(U, W1r, b1r, W2r, b2r, W3r, b3r, ws, 0);
            rmat_interleave<1><<<dim3(512), block, 0, stream>>>(ws, out);
        } else {
            rmat_mlp_mfma<2><<<grid, block, 0, stream>>>(U, W1r, b1r, W2r, b2r, W3r, b3r, out, 0);
        }
    }
}